// Round 16
// baseline (354.041 us; speedup 1.0000x reference)
//
#include <hip/hip_runtime.h>

#define NPRI 21504
#define BATCH 64
#define KTOP 1024

typedef unsigned long long u64;
typedef unsigned int u32;

// correctly-rounded f32 exp via f64 libm exp (validated: absmax 3e-8)
__device__ __forceinline__ float crexpf(float x) { return (float)exp((double)x); }

__device__ __forceinline__ u64 readlane64(u64 v, int lane) {
  int lo = __builtin_amdgcn_readlane((int)(u32)v, lane);
  int hi = __builtin_amdgcn_readlane((int)(u32)(v >> 32), lane);
  return ((u64)(u32)hi << 32) | (u64)(u32)lo;
}

__device__ __forceinline__ u64 score_key(float2 v, int idx) {
  float m = fmaxf(v.x, v.y);
  float e0 = crexpf(v.x - m);
  float e1 = crexpf(v.y - m);
  float s = e1 / (e0 + e1);            // exact f32 steps (validated)
  return ((u64)__float_as_uint(s) << 15) | (u64)(NPRI - 1 - idx);
}

// Key packing (validated): unique keys; desc u64 order == (score desc, idx asc)
// == lax.top_k stable order => any correct top-1024 structure is bit-exact.

// K1: per (image, group of 4 chunks): fused score+key, sort all 4 chunks in
// parallel (validated 55-phase bitonic, direction on LOCAL index), then
// in-block 4->2->1 top-1024 merges (validated half-cleaner + 10-phase clean).
// Block m=5 handles the lone chunk 20 (sort only). Output: 6 runs per image.
__global__ __launch_bounds__(256) void k_sortA(const float* __restrict__ confs,
                                               u64* __restrict__ runG) {
  const int b = blockIdx.x / 6;
  const int m = blockIdx.x % 6;
  const int t = threadIdx.x;
  __shared__ u64 ks[4096];             // 32 KB
  u64* dst = runG + ((size_t)b * 6 + m) * KTOP;
  if (m < 5) {
    const float2* cf = (const float2*)confs + (size_t)b * NPRI + m * 4096;
    for (int e = t; e < 4096; e += 256)
      ks[e] = score_key(cf[e], m * 4096 + e);
    // sort each 1024-chunk descending (j<1024 keeps pairs in-chunk)
    for (int k = 2; k <= 1024; k <<= 1) {
      for (int j = k >> 1; j > 0; j >>= 1) {
        __syncthreads();
        for (int e = t; e < 4096; e += 256) {
          int p = e ^ j;
          if (p > e) {
            int l = e & 1023;          // direction on LOCAL index
            u64 a = ks[e], q = ks[p];
            bool up = ((l & k) == 0);
            if ((a > q) != up) { ks[e] = q; ks[p] = a; }
          }
        }
      }
    }
    // stage 1: pairs (0,1),(2,3) -> top-1024 at bases 0, 2048
    __syncthreads();
    for (int e = t; e < 2048; e += 256) {
      int P = e >> 10, i = e & 1023;
      int base = P * 2048;
      u64 a = ks[base + i], q = ks[base + 2047 - i];   // reads [base+1024, base+2048)
      ks[base + i] = a > q ? a : q;                    // writes [base, base+1024)
    }
    for (int j = 512; j > 0; j >>= 1) {
      __syncthreads();
      for (int e = t; e < 2048; e += 256) {
        int P = e >> 10, l = e & 1023;
        int p = l ^ j;
        if (p > l) {
          int base = P * 2048;
          u64 a = ks[base + l], q = ks[base + p];
          if (a < q) { ks[base + l] = q; ks[base + p] = a; }
        }
      }
    }
    // stage 2: merge results at 0 and 2048 -> top-1024 at 0
    __syncthreads();
    for (int i = t; i < 1024; i += 256) {
      u64 a = ks[i], q = ks[2048 + 1023 - i];
      ks[i] = a > q ? a : q;
    }
    for (int j = 512; j > 0; j >>= 1) {
      __syncthreads();
      for (int l = t; l < 1024; l += 256) {
        int p = l ^ j;
        if (p > l) {
          u64 a = ks[l], q = ks[p];
          if (a < q) { ks[l] = q; ks[p] = a; }
        }
      }
    }
    __syncthreads();
    for (int i = t; i < 1024; i += 256) dst[i] = ks[i];
  } else {
    // lone chunk 20: plain validated 1024 bitonic sort
    const float2* cf = (const float2*)confs + (size_t)b * NPRI + 20 * 1024;
    for (int i = t; i < 1024; i += 256)
      ks[i] = score_key(cf[i], 20 * 1024 + i);
    for (int k = 2; k <= 1024; k <<= 1) {
      for (int j = k >> 1; j > 0; j >>= 1) {
        __syncthreads();
        for (int l = t; l < 1024; l += 256) {
          int p = l ^ j;
          if (p > l) {
            u64 a = ks[l], q = ks[p];
            bool up = ((l & k) == 0);
            if ((a > q) != up) { ks[l] = q; ks[p] = a; }
          }
        }
      }
    }
    __syncthreads();
    for (int i = t; i < 1024; i += 256) dst[i] = ks[i];
  }
}

// K2: per image: 6 runs -> top-1024 (3 parallel pair-merges, then 2 more merge
// stages; validated half-cleaner + clean), then validated decode + valid-ballot.
__global__ __launch_bounds__(256) void k_merge6(const u64* __restrict__ runG,
                                                const float* __restrict__ locs,
                                                const float* __restrict__ priors,
                                                float* __restrict__ boxF,
                                                float* __restrict__ scoreF,
                                                u64* __restrict__ validW) {
  const int b = blockIdx.x;
  const int t = threadIdx.x;
  __shared__ u64 M[6144];              // 48 KB
  const u64* src = runG + (size_t)b * 6 * KTOP;
  for (int i = t; i < 6144; i += 256) M[i] = src[i];
  __syncthreads();
  // stage 1: pairs (0,1),(2,3),(4,5) -> top-1024 at bases 0, 2048, 4096
  for (int e = t; e < 3072; e += 256) {
    int P = e >> 10, i = e & 1023;
    int base = P * 2048;
    u64 a = M[base + i], q = M[base + 2047 - i];
    M[base + i] = a > q ? a : q;
  }
  for (int j = 512; j > 0; j >>= 1) {
    __syncthreads();
    for (int e = t; e < 3072; e += 256) {
      int P = e >> 10, l = e & 1023;
      int p = l ^ j;
      if (p > l) {
        int base = P * 2048;
        u64 a = M[base + l], q = M[base + p];
        if (a < q) { M[base + l] = q; M[base + p] = a; }
      }
    }
  }
  // stage 2: merge bases 0 and 2048 -> 0
  __syncthreads();
  for (int i = t; i < 1024; i += 256) {
    u64 a = M[i], q = M[2048 + 1023 - i];
    M[i] = a > q ? a : q;
  }
  for (int j = 512; j > 0; j >>= 1) {
    __syncthreads();
    for (int l = t; l < 1024; l += 256) {
      int p = l ^ j;
      if (p > l) {
        u64 a = M[l], q = M[p];
        if (a < q) { M[l] = q; M[p] = a; }
      }
    }
  }
  // stage 3: merge bases 0 and 4096 -> 0
  __syncthreads();
  for (int i = t; i < 1024; i += 256) {
    u64 a = M[i], q = M[4096 + 1023 - i];
    M[i] = a > q ? a : q;
  }
  for (int j = 512; j > 0; j >>= 1) {
    __syncthreads();
    for (int l = t; l < 1024; l += 256) {
      int p = l ^ j;
      if (p > l) {
        u64 a = M[l], q = M[p];
        if (a < q) { M[l] = q; M[p] = a; }
      }
    }
  }
  __syncthreads();
  // decode top-1024: f32-stepwise (identical expressions to validated round 7)
  for (int i = t; i < KTOP; i += 256) {
    u64 K = M[i];
    float sv = __uint_as_float((u32)(K >> 15));
    int idx = NPRI - 1 - (int)(K & 0x7FFFu);
    float4 lo = ((const float4*)locs)[(size_t)b * NPRI + idx];
    float4 pr = ((const float4*)priors)[idx];
    float cx = pr.x + (lo.x * 0.1f) * pr.z;
    float cy = pr.y + (lo.y * 0.1f) * pr.w;
    float w  = pr.z * crexpf(lo.z * 0.2f);
    float h  = pr.w * crexpf(lo.w * 0.2f);
    float x1 = cx - w * 0.5f;
    float y1 = cy - h * 0.5f;
    float x2 = x1 + w;
    float y2 = y1 + h;
    size_t o = (size_t)b * KTOP + i;
    boxF[o * 4 + 0] = x1;
    boxF[o * 4 + 1] = y1;
    boxF[o * 4 + 2] = x2;
    boxF[o * 4 + 3] = y2;
    scoreF[o] = sv;
    u64 mask = __ballot(sv > 0.5f);       // wave covers group i>>6
    if ((t & 63) == 0) validW[(size_t)b * 16 + (i >> 6)] = mask;
  }
}

// K3: upper-triangle suppression bitmask, broadcast-friendly mapping
// (r12-validated: wave-uniform word => conflict-free broadcasts).
__global__ __launch_bounds__(256) void k_iou(const float* __restrict__ boxF,
                                             u64* __restrict__ sup) {
  const int b = blockIdx.y;
  const int g = blockIdx.x;            // row group 0..15
  __shared__ float4 BXS[KTOP];
  __shared__ float ARS[KTOP];
  const float4* bb = (const float4*)(boxF + (size_t)b * KTOP * 4);
  for (int l = g * 64 + threadIdx.x; l < KTOP; l += 256) {
    float4 v = bb[l];
    BXS[l] = v;
    ARS[l] = fmaxf(v.z - v.x, 0.0f) * fmaxf(v.w - v.y, 0.0f);
  }
  __syncthreads();
  const int r = threadIdx.x & 63;
  const int v = threadIdx.x >> 6;      // wave 0..3
  const int i = g * 64 + r;
  const float4 bi = BXS[i];
  const float a = ARS[i];
  for (int w = g + v; w < 16; w += 4) {
    u64 word = 0;
    const int jbase = w * 64;
    for (int jb = 0; jb < 64; jb++) {
      int j = jbase + jb;
      float4 bj = BXS[j];              // broadcast (w uniform in wave)
      float aj = ARS[j];
      float lx = fmaxf(bi.x, bj.x);
      float ly = fmaxf(bi.y, bj.y);
      float rx = fminf(bi.z, bj.z);
      float ry = fminf(bi.w, bj.w);
      float iw = fmaxf(rx - lx, 0.0f);
      float ih = fmaxf(ry - ly, 0.0f);
      float inter = iw * ih;
      float uni = (a + aj) - inter;
      float iou = inter / fmaxf(uni, 1e-9f);
      if (iou > 0.4f) word |= (1ULL << jb);
    }
    if (w == g) word &= (r == 63) ? 0ULL : (~0ULL << (r + 1));   // j > i
    sup[((size_t)b * KTOP + i) * 16 + w] = word;
  }
}

// K4: group-synchronous greedy NMS (validated round 12): ctz+readlane chain
// over kept bits only + register prefetch double-buffer. Exact greedy semantics.
__global__ __launch_bounds__(256) void k_scan(const u64* __restrict__ sup,
                                              const u64* __restrict__ validW,
                                              const float* __restrict__ boxF,
                                              const float* __restrict__ scoreF,
                                              float* __restrict__ out) {
  const int b = blockIdx.x;
  const int t = threadIdx.x;
  __shared__ u64 rows[2][64][16];      // 16 KB double buffer
  __shared__ u64 remv[16];
  __shared__ u64 keepW[16];
  __shared__ u64 vW[16];
  const u64* supB = sup + (size_t)b * KTOP * 16;
  for (int l = t; l < 1024; l += 256)
    rows[0][l >> 4][l & 15] = supB[l];
  if (t < 16) { remv[t] = 0; vW[t] = validW[(size_t)b * 16 + t]; }
  __syncthreads();
  for (int g = 0; g < 16; g++) {
    const int cur = g & 1;
    u64 pf0, pf1, pf2, pf3;
    if (g < 15) {
      const u64* nsrc = supB + (size_t)(g + 1) * 1024;
      pf0 = nsrc[t];
      pf1 = nsrc[t + 256];
      pf2 = nsrc[t + 512];
      pf3 = nsrc[t + 768];
    }
    if (t < 64) {
      u64 diag = rows[cur][t][g];        // lane i: row i's intra-group word
      u64 alive = vW[g] & ~remv[g];      // wave-uniform
      u64 keep = 0;
      u64 m = alive;
      while (m) {
        int i = __builtin_ctzll(m);
        keep |= (1ULL << i);
        u64 row = readlane64(diag, i);   // row i has only bits j>i
        alive &= ~row;
        m = (i == 63) ? 0ULL : (alive & (~0ULL << (i + 1)));
      }
      if (t == 0) keepW[g] = keep;
    }
    __syncthreads();
    {
      u64 kw = keepW[g];
      int w = t & 15;
      if (w > g) {
        int i0 = (t >> 4) * 4;
        u64 acc = 0;
        for (int i = i0; i < i0 + 4; i++)
          if ((kw >> i) & 1ULL) acc |= rows[cur][i][w];
        if (acc) atomicOr(&remv[w], acc);
      }
    }
    if (g < 15) {
      u64* dstb = &rows[cur ^ 1][0][0];
      dstb[t] = pf0;
      dstb[t + 256] = pf1;
      dstb[t + 512] = pf2;
      dstb[t + 768] = pf3;
    }
    __syncthreads();   // remv + next buffer visible
  }
  const float* bb = boxF + (size_t)b * KTOP * 4;
  const float* sc = scoreF + (size_t)b * KTOP;
  for (int i = t; i < KTOP; i += 256) {
    float kf = ((keepW[i >> 6] >> (i & 63)) & 1ULL) ? 1.0f : 0.0f;
    size_t o5 = ((size_t)b * KTOP + i) * 5;
    out[o5 + 0] = bb[i * 4 + 0] * kf;
    out[o5 + 1] = bb[i * 4 + 1] * kf;
    out[o5 + 2] = bb[i * 4 + 2] * kf;
    out[o5 + 3] = bb[i * 4 + 3] * kf;
    out[o5 + 4] = sc[i] * kf;
    out[(size_t)BATCH * KTOP * 5 + (size_t)b * KTOP + i] = kf;
  }
}

extern "C" void kernel_launch(void* const* d_in, const int* in_sizes, int n_in,
                              void* d_out, int out_size, void* d_ws, size_t ws_size,
                              hipStream_t stream) {
  const float* locs = nullptr;
  const float* confs = nullptr;
  const float* priors = nullptr;
  for (int i = 0; i < n_in; i++) {
    if (in_sizes[i] == BATCH * NPRI * 4) locs = (const float*)d_in[i];
    else if (in_sizes[i] == BATCH * NPRI * 2) confs = (const float*)d_in[i];
    else if (in_sizes[i] == NPRI * 4) priors = (const float*)d_in[i];
  }
  float* out = (float*)d_out;   // f32: [B,K,5] dets ++ [B,K] keep

  char* ws = (char*)d_ws;
  size_t off = 0;
  u64* runG = (u64*)(ws + off);          // 64*6*1024*8 = 3,145,728 (dead after k_merge6)
  u64* sup = (u64*)(ws + off);           // alias: 8,388,608 (written by k_iou after)
  off += (size_t)BATCH * KTOP * 16 * 8;
  float* boxF = (float*)(ws + off);      off += (size_t)BATCH * KTOP * 4 * 4;   // 1,048,576
  float* scoreF = (float*)(ws + off);    off += (size_t)BATCH * KTOP * 4;       //   262,144
  u64* validW = (u64*)(ws + off);        off += (size_t)BATCH * 16 * 8;         //     8,192
  // total ~9.7 MB

  k_sortA<<<BATCH * 6, 256, 0, stream>>>(confs, runG);
  k_merge6<<<BATCH, 256, 0, stream>>>(runG, locs, priors, boxF, scoreF, validW);
  k_iou<<<dim3(16, BATCH), 256, 0, stream>>>(boxF, sup);
  k_scan<<<BATCH, 256, 0, stream>>>(sup, validW, boxF, scoreF, out);
}

// Round 17
// 269.609 us; speedup vs baseline: 1.3132x; 1.3132x over previous
//
#include <hip/hip_runtime.h>

#define NPRI 21504
#define BATCH 64
#define KTOP 1024
#define NCH 21

typedef unsigned long long u64;
typedef unsigned int u32;

// correctly-rounded f32 exp via f64 libm exp (validated: absmax 3e-8)
__device__ __forceinline__ float crexpf(float x) { return (float)exp((double)x); }

__device__ __forceinline__ u64 readlane64(u64 v, int lane) {
  int lo = __builtin_amdgcn_readlane((int)(u32)v, lane);
  int hi = __builtin_amdgcn_readlane((int)(u32)(v >> 32), lane);
  return ((u64)(u32)hi << 32) | (u64)(u32)lo;
}

// Key packing (validated): key = (score_bits<<15) | (NPRI-1-idx). Unique keys;
// desc u64 order == (score desc, idx asc) == lax.top_k stable order => any
// correct top-1024 structure is bit-exact.

// K1: fused score + per-chunk bitonic sort (r12-validated, 1344 blocks, 8 KB).
__global__ __launch_bounds__(256) void k_sort(const float* __restrict__ confs,
                                              u64* __restrict__ keyG) {
  const int b = blockIdx.x / NCH;
  const int c = blockIdx.x % NCH;
  __shared__ u64 ks[KTOP];
  const float2* cf = (const float2*)confs + (size_t)b * NPRI + c * KTOP;
  for (int i = threadIdx.x; i < KTOP; i += 256) {
    float2 v = cf[i];
    float m = fmaxf(v.x, v.y);
    float e0 = crexpf(v.x - m);
    float e1 = crexpf(v.y - m);
    float s = e1 / (e0 + e1);          // exact f32 steps (validated)
    int idx = c * KTOP + i;
    ks[i] = ((u64)__float_as_uint(s) << 15) | (u64)(NPRI - 1 - idx);
  }
  for (int k = 2; k <= KTOP; k <<= 1) {
    for (int j = k >> 1; j > 0; j >>= 1) {
      __syncthreads();
      for (int l = threadIdx.x; l < KTOP; l += 256) {
        int p = l ^ j;
        if (p > l) {
          u64 a = ks[l], q = ks[p];
          bool up = ((l & k) == 0);
          if ((a > q) != up) { ks[l] = q; ks[p] = a; }
        }
      }
    }
  }
  __syncthreads();
  u64* dst = keyG + (size_t)b * NPRI + (size_t)c * KTOP;
  for (int i = threadIdx.x; i < KTOP; i += 256) dst[i] = ks[i];
}

// K2: 3 blocks/image: serially merge 7 runs -> top-1024 (r8-validated serial
// half-cleaner + clean loop, 7 runs instead of 21). 16 KB LDS, 192 blocks.
__global__ __launch_bounds__(256) void k_merge7(const u64* __restrict__ keyG,
                                                u64* __restrict__ midG) {
  const int b = blockIdx.x / 3;
  const int p3 = blockIdx.x % 3;
  __shared__ u64 A[KTOP];
  __shared__ u64 Bv[KTOP];
  const u64* src = keyG + ((size_t)b * NCH + p3 * 7) * KTOP;
  for (int i = threadIdx.x; i < KTOP; i += 256) A[i] = src[i];
  for (int c = 1; c < 7; c++) {
    __syncthreads();
    for (int i = threadIdx.x; i < KTOP; i += 256)
      Bv[i] = src[(size_t)c * KTOP + (KTOP - 1 - i)];   // reversed: asc
    __syncthreads();
    for (int i = threadIdx.x; i < KTOP; i += 256)
      if (Bv[i] > A[i]) A[i] = Bv[i];                    // half-cleaner
    for (int j = KTOP / 2; j > 0; j >>= 1) {             // clean -> desc
      __syncthreads();
      for (int l = threadIdx.x; l < KTOP; l += 256) {
        int p = l ^ j;
        if (p > l) {
          u64 a = A[l], q = A[p];
          if (a < q) { A[l] = q; A[p] = a; }
        }
      }
    }
  }
  __syncthreads();
  u64* d = midG + ((size_t)b * 3 + p3) * KTOP;
  for (int i = threadIdx.x; i < KTOP; i += 256) d[i] = A[i];
}

// K3: per image: merge 3 mids -> top-1024, then validated decode + valid-ballot.
__global__ __launch_bounds__(256) void k_merge3(const u64* __restrict__ midG,
                                                const float* __restrict__ locs,
                                                const float* __restrict__ priors,
                                                float* __restrict__ boxF,
                                                float* __restrict__ scoreF,
                                                u64* __restrict__ validW) {
  const int b = blockIdx.x;
  const int t = threadIdx.x;
  __shared__ u64 A[KTOP];
  __shared__ u64 Bv[KTOP];
  const u64* src = midG + (size_t)b * 3 * KTOP;
  for (int i = t; i < KTOP; i += 256) A[i] = src[i];
  for (int c = 1; c < 3; c++) {
    __syncthreads();
    for (int i = t; i < KTOP; i += 256)
      Bv[i] = src[(size_t)c * KTOP + (KTOP - 1 - i)];
    __syncthreads();
    for (int i = t; i < KTOP; i += 256)
      if (Bv[i] > A[i]) A[i] = Bv[i];
    for (int j = KTOP / 2; j > 0; j >>= 1) {
      __syncthreads();
      for (int l = t; l < KTOP; l += 256) {
        int p = l ^ j;
        if (p > l) {
          u64 a = A[l], q = A[p];
          if (a < q) { A[l] = q; A[p] = a; }
        }
      }
    }
  }
  __syncthreads();
  // decode top-1024: f32-stepwise (identical expressions to validated round 7)
  for (int i = t; i < KTOP; i += 256) {
    u64 K = A[i];
    float sv = __uint_as_float((u32)(K >> 15));
    int idx = NPRI - 1 - (int)(K & 0x7FFFu);
    float4 lo = ((const float4*)locs)[(size_t)b * NPRI + idx];
    float4 pr = ((const float4*)priors)[idx];
    float cx = pr.x + (lo.x * 0.1f) * pr.z;
    float cy = pr.y + (lo.y * 0.1f) * pr.w;
    float w  = pr.z * crexpf(lo.z * 0.2f);
    float h  = pr.w * crexpf(lo.w * 0.2f);
    float x1 = cx - w * 0.5f;
    float y1 = cy - h * 0.5f;
    float x2 = x1 + w;
    float y2 = y1 + h;
    size_t o = (size_t)b * KTOP + i;
    boxF[o * 4 + 0] = x1;
    boxF[o * 4 + 1] = y1;
    boxF[o * 4 + 2] = x2;
    boxF[o * 4 + 3] = y2;
    scoreF[o] = sv;
    u64 mask = __ballot(sv > 0.5f);       // wave covers group i>>6
    if ((t & 63) == 0) validW[(size_t)b * 16 + (i >> 6)] = mask;
  }
}

// K4: upper-triangle suppression bitmask, balanced 40-task mapping
// (r13-validated correct: block=(g, 4-word chunk), wave-uniform word =>
// conflict-free broadcasts; words w<g never written nor read).
__global__ __launch_bounds__(256) void k_iou(const float* __restrict__ boxF,
                                             u64* __restrict__ sup) {
  const int b = blockIdx.y;
  int task = blockIdx.x;               // 0..39
  int g = 0, base = 0;
  for (int gg = 0; gg < 16; gg++) {
    int cg = (16 - gg + 3) >> 2;
    if (task < base + cg) { g = gg; break; }
    base += cg;
  }
  const int c = task - base;
  const int w0 = g + 4 * c;            // first word of this chunk
  __shared__ float4 BXS[256];
  __shared__ float ARS[256];
  const float4* bb = (const float4*)(boxF + (size_t)b * KTOP * 4);
  {
    int j = w0 * 64 + threadIdx.x;
    if (j < KTOP) {
      float4 v = bb[j];
      BXS[threadIdx.x] = v;
      ARS[threadIdx.x] = fmaxf(v.z - v.x, 0.0f) * fmaxf(v.w - v.y, 0.0f);
    }
  }
  const int r = threadIdx.x & 63;
  const int v = threadIdx.x >> 6;      // wave 0..3
  const int i = g * 64 + r;
  float4 bi = bb[i];
  float a = fmaxf(bi.z - bi.x, 0.0f) * fmaxf(bi.w - bi.y, 0.0f);
  __syncthreads();
  const int w = w0 + v;
  if (w < 16) {
    u64 word = 0;
    const int lbase = v * 64;
    for (int jb = 0; jb < 64; jb++) {
      int lj = lbase + jb;
      float4 bj = BXS[lj];             // broadcast (w uniform in wave)
      float aj = ARS[lj];
      float lx = fmaxf(bi.x, bj.x);
      float ly = fmaxf(bi.y, bj.y);
      float rx = fminf(bi.z, bj.z);
      float ry = fminf(bi.w, bj.w);
      float iw = fmaxf(rx - lx, 0.0f);
      float ih = fmaxf(ry - ly, 0.0f);
      float inter = iw * ih;
      float uni = (a + aj) - inter;
      float iou = inter / fmaxf(uni, 1e-9f);
      if (iou > 0.4f) word |= (1ULL << jb);
    }
    if (w == g) word &= (r == 63) ? 0ULL : (~0ULL << (r + 1));   // j > i
    sup[((size_t)b * KTOP + i) * 16 + w] = word;
  }
}

// K5: group-synchronous greedy NMS (r12-validated): ctz+readlane chain over
// kept bits only + register prefetch double-buffer. Exact greedy semantics.
__global__ __launch_bounds__(256) void k_scan(const u64* __restrict__ sup,
                                              const u64* __restrict__ validW,
                                              const float* __restrict__ boxF,
                                              const float* __restrict__ scoreF,
                                              float* __restrict__ out) {
  const int b = blockIdx.x;
  const int t = threadIdx.x;
  __shared__ u64 rows[2][64][16];      // 16 KB double buffer
  __shared__ u64 remv[16];
  __shared__ u64 keepW[16];
  __shared__ u64 vW[16];
  const u64* supB = sup + (size_t)b * KTOP * 16;
  for (int l = t; l < 1024; l += 256)
    rows[0][l >> 4][l & 15] = supB[l];
  if (t < 16) { remv[t] = 0; vW[t] = validW[(size_t)b * 16 + t]; }
  __syncthreads();
  for (int g = 0; g < 16; g++) {
    const int cur = g & 1;
    u64 pf0, pf1, pf2, pf3;
    if (g < 15) {
      const u64* nsrc = supB + (size_t)(g + 1) * 1024;
      pf0 = nsrc[t];
      pf1 = nsrc[t + 256];
      pf2 = nsrc[t + 512];
      pf3 = nsrc[t + 768];
    }
    if (t < 64) {
      u64 diag = rows[cur][t][g];        // lane i: row i's intra-group word
      u64 alive = vW[g] & ~remv[g];      // wave-uniform
      u64 keep = 0;
      u64 m = alive;
      while (m) {
        int i = __builtin_ctzll(m);
        keep |= (1ULL << i);
        u64 row = readlane64(diag, i);   // row i has only bits j>i
        alive &= ~row;
        m = (i == 63) ? 0ULL : (alive & (~0ULL << (i + 1)));
      }
      if (t == 0) keepW[g] = keep;
    }
    __syncthreads();
    {
      u64 kw = keepW[g];
      int w = t & 15;
      if (w > g) {
        int i0 = (t >> 4) * 4;
        u64 acc = 0;
        for (int i = i0; i < i0 + 4; i++)
          if ((kw >> i) & 1ULL) acc |= rows[cur][i][w];
        if (acc) atomicOr(&remv[w], acc);
      }
    }
    if (g < 15) {
      u64* dstb = &rows[cur ^ 1][0][0];
      dstb[t] = pf0;
      dstb[t + 256] = pf1;
      dstb[t + 512] = pf2;
      dstb[t + 768] = pf3;
    }
    __syncthreads();   // remv + next buffer visible
  }
  const float* bb = boxF + (size_t)b * KTOP * 4;
  const float* sc = scoreF + (size_t)b * KTOP;
  for (int i = t; i < KTOP; i += 256) {
    float kf = ((keepW[i >> 6] >> (i & 63)) & 1ULL) ? 1.0f : 0.0f;
    size_t o5 = ((size_t)b * KTOP + i) * 5;
    out[o5 + 0] = bb[i * 4 + 0] * kf;
    out[o5 + 1] = bb[i * 4 + 1] * kf;
    out[o5 + 2] = bb[i * 4 + 2] * kf;
    out[o5 + 3] = bb[i * 4 + 3] * kf;
    out[o5 + 4] = sc[i] * kf;
    out[(size_t)BATCH * KTOP * 5 + (size_t)b * KTOP + i] = kf;
  }
}

extern "C" void kernel_launch(void* const* d_in, const int* in_sizes, int n_in,
                              void* d_out, int out_size, void* d_ws, size_t ws_size,
                              hipStream_t stream) {
  const float* locs = nullptr;
  const float* confs = nullptr;
  const float* priors = nullptr;
  for (int i = 0; i < n_in; i++) {
    if (in_sizes[i] == BATCH * NPRI * 4) locs = (const float*)d_in[i];
    else if (in_sizes[i] == BATCH * NPRI * 2) confs = (const float*)d_in[i];
    else if (in_sizes[i] == NPRI * 4) priors = (const float*)d_in[i];
  }
  float* out = (float*)d_out;   // f32: [B,K,5] dets ++ [B,K] keep

  char* ws = (char*)d_ws;
  size_t off = 0;
  u64* keyG = (u64*)(ws + off);          // B*21*1024*8 = 11,010,048
  u64* sup = (u64*)(ws + off);           // alias: keyG dead after k_merge7 reads,
                                         // sup written by k_iou later (8,388,608)
  off += (size_t)BATCH * NCH * KTOP * 8;
  u64* midG = (u64*)(ws + off);          off += (size_t)BATCH * 3 * KTOP * 8;   // 1,572,864
  float* boxF = (float*)(ws + off);      off += (size_t)BATCH * KTOP * 4 * 4;   // 1,048,576
  float* scoreF = (float*)(ws + off);    off += (size_t)BATCH * KTOP * 4;       //   262,144
  u64* validW = (u64*)(ws + off);        off += (size_t)BATCH * 16 * 8;         //     8,192
  // total ~13.9 MB

  k_sort<<<BATCH * NCH, 256, 0, stream>>>(confs, keyG);
  k_merge7<<<BATCH * 3, 256, 0, stream>>>(keyG, midG);
  k_merge3<<<BATCH, 256, 0, stream>>>(midG, locs, priors, boxF, scoreF, validW);
  k_iou<<<dim3(40, BATCH), 256, 0, stream>>>(boxF, sup);
  k_scan<<<BATCH, 256, 0, stream>>>(sup, validW, boxF, scoreF, out);
}